// Round 4
// baseline (485.054 us; speedup 1.0000x reference)
//
#include <hip/hip_runtime.h>
#include <hip/hip_fp16.h>
#include <math.h>

#define TAU_INV 5.0f      // 1 / 0.2
#define LOG2E   1.4426950408889634f

typedef _Float16 half2v __attribute__((ext_vector_type(2)));

// raw gfx950 transcendentals: v_exp_f32 is 2^x, v_log_f32 is log2(x)
__device__ __forceinline__ float fast_exp2(float x) { return __builtin_amdgcn_exp2f(x); }
__device__ __forceinline__ float fast_log2(float x) { return __builtin_amdgcn_logf(x); }

// ---------------------------------------------------------------------------
__global__ void init_sumd(double* __restrict__ seg_sumd, int n) {
    int i = blockIdx.x * blockDim.x + threadIdx.x;
    if (i < n) seg_sumd[i] = 0.0;
}

// exp(z) as a double, via 2^n * exp2(r).  z in ~[-700, +700] is safe.
__device__ __forceinline__ double exp_double(float z) {
    float y = z * LOG2E;
    float n = rintf(y);
    float r = y - n;                 // |r| <= 0.5
    float f = fast_exp2(r);
    long long e = (long long)n + 1023;
    if (e < 1)    e = 1;             // clamp: astronomically small, irrelevant
    if (e > 2046) e = 2046;          // clamp: cannot happen for this data
    double scale = __longlong_as_double(e << 52);
    return (double)f * scale;
}

// log2 of a positive normal double, to float precision.
__device__ __forceinline__ float log2_of_double(double v) {
    unsigned long long b = __double_as_longlong(v);
    int ex = (int)((b >> 52) & 0x7FFULL) - 1023;
    double m = __longlong_as_double((b & 0xFFFFFFFFFFFFFULL) | 0x3FF0000000000000ULL);
    return (float)ex + fast_log2((float)m);
}

// ---------------------------------------------------------------------------
// Merged fp32 GEMM (R5 structure — known 147 us; do NOT hand-pipeline: R4's
// serial register stream and R6's cross-barrier prefetch regs both lost).
// X = [Xu; Xi] (75000 x 256); Q = X@Wq+bq, K = X@Wk+bk; A staged once.
// Epilogue: fp16 INTERLEAVED rows  QK[gr*256 + 0..127] = Q, [128..255] = K.
// ---------------------------------------------------------------------------
__global__ __launch_bounds__(256) void gemm_qk_merged(
    const float* __restrict__ Xu, const float* __restrict__ Xi,
    const float* __restrict__ Wq, const float* __restrict__ bq,
    const float* __restrict__ Wk, const float* __restrict__ bk,
    __half* __restrict__ QK,
    int U, int I, int D)
{
    __shared__ float As_t[16][68];
    __shared__ float Bs_q[16][132];
    __shared__ float Bs_k[16][132];

    const int tid  = threadIdx.x;
    const int row0 = blockIdx.x * 64;
    const int tr   = tid >> 5;
    const int tc   = tid & 31;

    float4 accq[8], acck[8];
#pragma unroll
    for (int i = 0; i < 8; ++i) {
        accq[i] = make_float4(0.f, 0.f, 0.f, 0.f);
        acck[i] = make_float4(0.f, 0.f, 0.f, 0.f);
    }

    const int ar  = tid >> 2;
    const int akq = (tid & 3) * 4;

    for (int k0 = 0; k0 < D; k0 += 16) {
        {
            int gr = row0 + ar;
            float4 v = make_float4(0.f, 0.f, 0.f, 0.f);
            if (gr < U)            v = *(const float4*)&Xu[(size_t)gr * D + k0 + akq];
            else if (gr - U < I)   v = *(const float4*)&Xi[(size_t)(gr - U) * D + k0 + akq];
            As_t[akq + 0][ar] = v.x;
            As_t[akq + 1][ar] = v.y;
            As_t[akq + 2][ar] = v.z;
            As_t[akq + 3][ar] = v.w;
        }
#pragma unroll
        for (int t = 0; t < 2; ++t) {
            int idx = tid + t * 256;
            int r  = idx >> 5;
            int c4 = (idx & 31) * 4;
            float4 vq = *(const float4*)&Wq[(size_t)(k0 + r) * 128 + c4];
            float4 vk = *(const float4*)&Wk[(size_t)(k0 + r) * 128 + c4];
            *(float4*)&Bs_q[r][c4] = vq;
            *(float4*)&Bs_k[r][c4] = vk;
        }
        __syncthreads();

#pragma unroll
        for (int kk = 0; kk < 16; ++kk) {
            float4 a0  = *(const float4*)&As_t[kk][tr * 8];
            float4 a1  = *(const float4*)&As_t[kk][tr * 8 + 4];
            float4 bqv = *(const float4*)&Bs_q[kk][tc * 4];
            float4 bkv = *(const float4*)&Bs_k[kk][tc * 4];
            float a[8] = {a0.x, a0.y, a0.z, a0.w, a1.x, a1.y, a1.z, a1.w};
#pragma unroll
            for (int i = 0; i < 8; ++i) {
                accq[i].x += a[i] * bqv.x;
                accq[i].y += a[i] * bqv.y;
                accq[i].z += a[i] * bqv.z;
                accq[i].w += a[i] * bqv.w;
                acck[i].x += a[i] * bkv.x;
                acck[i].y += a[i] * bkv.y;
                acck[i].z += a[i] * bkv.z;
                acck[i].w += a[i] * bkv.w;
            }
        }
        __syncthreads();
    }

    const float4 bbq = *(const float4*)&bq[tc * 4];
    const float4 bbk = *(const float4*)&bk[tc * 4];
    const int NT = U + I;
#pragma unroll
    for (int i = 0; i < 8; ++i) {
        int gr = row0 + tr * 8 + i;
        if (gr < NT) {
            __half2 q01 = __floats2half2_rn(accq[i].x + bbq.x, accq[i].y + bbq.y);
            __half2 q23 = __floats2half2_rn(accq[i].z + bbq.z, accq[i].w + bbq.w);
            __half2 k01 = __floats2half2_rn(acck[i].x + bbk.x, acck[i].y + bbk.y);
            __half2 k23 = __floats2half2_rn(acck[i].z + bbk.z, acck[i].w + bbk.w);
            uint2 pq, pk;
            pq.x = *(const unsigned int*)&q01;
            pq.y = *(const unsigned int*)&q23;
            pk.x = *(const unsigned int*)&k01;
            pk.y = *(const unsigned int*)&k23;
            *(uint2*)&QK[(size_t)gr * 256 + tc * 4]       = pq;   // Q half
            *(uint2*)&QK[(size_t)gr * 256 + 128 + tc * 4] = pk;   // K half
        }
    }
}

// ---------------------------------------------------------------------------
// Fused BOTH-direction edge kernel, 8 lanes per edge.
// Each lane loads 8 x 16B (256 B in flight): 2 chunks from each of the 4
// row-halves {Q_user, K_user, Q_item, K_item}.  Dual fdot2 accumulators,
// 3-step butterfly reduce over the 8-lane group; lanes 0/1 handle ui/iu tails:
//   z = (d - log(-log(noise))) / tau ; store z ; atomicAdd seg_sumd += exp(z)
// (no max pass: softmax is shift-invariant; the double accumulator absorbs
//  the dynamic range, and the norm pass works in log2 domain).
// Streaming operands (indices, noise, out) are nontemporal to keep QK in L2.
// ---------------------------------------------------------------------------
__global__ __launch_bounds__(256) void edge_w_both(
    const __half* __restrict__ QK,
    const int* __restrict__ rows, const int* __restrict__ cols,
    const float* __restrict__ noise_ui, const float* __restrict__ noise_iu,
    float* __restrict__ out, double* __restrict__ seg_sumd, int U, int E)
{
    const int gtid = blockIdx.x * 256 + threadIdx.x;
    const int eid  = gtid >> 3;
    if (eid >= E) return;
    const int hl = threadIdx.x & 7;

    const int r = __builtin_nontemporal_load(&rows[eid]);
    const int c = __builtin_nontemporal_load(&cols[eid]);
    const __half* urow = QK + (size_t)r * 256;
    const __half* irow = QK + (size_t)(U + c) * 256;

    // lane covers halves [hl*16, hl*16+16) of each 128-half row-half
    const uint4 qu0 = *(const uint4*)(urow + hl * 16);
    const uint4 qu1 = *(const uint4*)(urow + hl * 16 + 8);
    const uint4 ku0 = *(const uint4*)(urow + 128 + hl * 16);
    const uint4 ku1 = *(const uint4*)(urow + 128 + hl * 16 + 8);
    const uint4 qi0 = *(const uint4*)(irow + hl * 16);
    const uint4 qi1 = *(const uint4*)(irow + hl * 16 + 8);
    const uint4 ki0 = *(const uint4*)(irow + 128 + hl * 16);
    const uint4 ki1 = *(const uint4*)(irow + 128 + hl * 16 + 8);

    float d0 = 0.0f, d1 = 0.0f;
    {
        const half2v* a0 = (const half2v*)&qu0;   // qu0,qu1 contiguous? no — treat separately
        const half2v* b0 = (const half2v*)&ki0;
        const half2v* a1 = (const half2v*)&qi0;
        const half2v* b1 = (const half2v*)&ku0;
#pragma unroll
        for (int t = 0; t < 4; ++t) {
            d0 = __builtin_amdgcn_fdot2(a0[t], b0[t], d0, false);
            d1 = __builtin_amdgcn_fdot2(a1[t], b1[t], d1, false);
        }
        const half2v* a0b = (const half2v*)&qu1;
        const half2v* b0b = (const half2v*)&ki1;
        const half2v* a1b = (const half2v*)&qi1;
        const half2v* b1b = (const half2v*)&ku1;
#pragma unroll
        for (int t = 0; t < 4; ++t) {
            d0 = __builtin_amdgcn_fdot2(a0b[t], b0b[t], d0, false);
            d1 = __builtin_amdgcn_fdot2(a1b[t], b1b[t], d1, false);
        }
    }
    d0 += __shfl_xor(d0, 4);  d1 += __shfl_xor(d1, 4);
    d0 += __shfl_xor(d0, 2);  d1 += __shfl_xor(d1, 2);
    d0 += __shfl_xor(d0, 1);  d1 += __shfl_xor(d1, 1);

    if (hl < 2) {
        const int g  = hl;                      // 0 = ui, 1 = iu
        const float d  = g ? d1 : d0;
        const float nz = g ? __builtin_nontemporal_load(&noise_iu[eid])
                           : __builtin_nontemporal_load(&noise_ui[eid]);
        const float zz = (d - __logf(-__logf(nz))) * TAU_INV;
        const int s  = g ? (U + c) : r;
        __builtin_nontemporal_store(zz, &out[(size_t)g * E + eid]);
        atomicAdd(&seg_sumd[s], exp_double(zz));
    }
}

// ---------------------------------------------------------------------------
// out = exp(z) / S[seg]  computed as  exp2(z*log2e - log2(S))  (all float,
// no overflow since the argument is <= ~0).  Vectorized 2 elems/thread.
// ---------------------------------------------------------------------------
__global__ void edge_norm2v(float* __restrict__ z,
                            const int* __restrict__ rows, const int* __restrict__ cols,
                            const double* __restrict__ seg_sumd, int U, int E)
{
    int p = blockIdx.x * blockDim.x + threadIdx.x;
    int i = p * 2;
    if (i >= 2 * E) return;
    const bool iu  = (i >= E);
    const int base = iu ? (i - E) : i;
    const int off  = iu ? U : 0;
    const int* idx = iu ? cols : rows;
    int2 rc;
    rc.x = __builtin_nontemporal_load(&idx[base]);
    rc.y = __builtin_nontemporal_load(&idx[base + 1]);
    float2 zz;
    zz.x = __builtin_nontemporal_load(&z[i]);
    zz.y = __builtin_nontemporal_load(&z[i + 1]);
    float l0 = log2_of_double(seg_sumd[off + rc.x]);
    float l1 = log2_of_double(seg_sumd[off + rc.y]);
    float o0 = fast_exp2(zz.x * LOG2E - l0);
    float o1 = fast_exp2(zz.y * LOG2E - l1);
    __builtin_nontemporal_store(o0, &z[i]);
    __builtin_nontemporal_store(o1, &z[i + 1]);
}

__global__ void edge_norm2(float* __restrict__ z,
                           const int* __restrict__ rows, const int* __restrict__ cols,
                           const double* __restrict__ seg_sumd, int U, int E)
{
    int i = blockIdx.x * blockDim.x + threadIdx.x;
    if (i >= 2 * E) return;
    int s = (i < E) ? rows[i] : (U + cols[i - E]);
    float l = log2_of_double(seg_sumd[s]);
    z[i] = fast_exp2(z[i] * LOG2E - l);
}

// ---------------------------------------------------------------------------
extern "C" void kernel_launch(void* const* d_in, const int* in_sizes, int n_in,
                              void* d_out, int out_size, void* d_ws, size_t ws_size,
                              hipStream_t stream)
{
    const float* user_embed = (const float*)d_in[0];
    const float* item_embed = (const float*)d_in[1];
    const float* Wq = (const float*)d_in[2];
    const float* bq = (const float*)d_in[3];
    const float* Wk = (const float*)d_in[4];
    const float* bk = (const float*)d_in[5];
    const int* ui_rows    = (const int*)d_in[6];
    const int* ui_cols    = (const int*)d_in[7];
    const float* noise_ui = (const float*)d_in[8];
    const float* noise_iu = (const float*)d_in[9];

    const int H = in_sizes[3];           // 128
    const int D = in_sizes[2] / H;       // 256
    const int U = in_sizes[0] / D;       // 50000
    const int I = in_sizes[1] / D;       // 25000
    const int E = in_sizes[6];           // 1600000

    const int nseg = U + I;

    // workspace: QK (fp16 interleaved, (U+I) x 256) | seg_sumd (double)
    char* wsc = (char*)d_ws;
    __half* QK = (__half*)wsc;        wsc += (size_t)nseg * 256 * sizeof(__half);
    double* seg_sumd = (double*)wsc;  wsc += (size_t)nseg * sizeof(double);

    float* out = (float*)d_out;       // [z_ui | z_iu] -> normalized in place

    init_sumd<<<(nseg + 255) / 256, 256, 0, stream>>>(seg_sumd, nseg);

    const int gblocks = (nseg + 63) / 64;
    gemm_qk_merged<<<gblocks, 256, 0, stream>>>(user_embed, item_embed,
                                                Wq, bq, Wk, bk, QK, U, I, D);

    const int eblocks = (int)(((long long)E * 8 + 255) / 256);
    edge_w_both<<<eblocks, 256, 0, stream>>>(QK, ui_rows, ui_cols,
                                             noise_ui, noise_iu,
                                             out, seg_sumd, U, E);

    if ((E & 1) == 0) {
        const int vblocks = (E + 255) / 256;   // E pairs cover 2E elements
        edge_norm2v<<<vblocks, 256, 0, stream>>>(out, ui_rows, ui_cols,
                                                 seg_sumd, U, E);
    } else {
        const int sblocks = (2 * E + 255) / 256;
        edge_norm2<<<sblocks, 256, 0, stream>>>(out, ui_rows, ui_cols,
                                                seg_sumd, U, E);
    }
}

// Round 5
// 439.028 us; speedup vs baseline: 1.1048x; 1.1048x over previous
//
#include <hip/hip_runtime.h>
#include <hip/hip_fp16.h>
#include <math.h>

#define TAU_INV 5.0f      // 1 / 0.2
#define LOG2E   1.4426950408889634f

typedef _Float16 half2v __attribute__((ext_vector_type(2)));
typedef _Float16 f16x8  __attribute__((ext_vector_type(8)));
typedef float    f32x4  __attribute__((ext_vector_type(4)));

// raw gfx950 transcendentals: v_exp_f32 is 2^x, v_log_f32 is log2(x)
__device__ __forceinline__ float fast_exp2(float x) { return __builtin_amdgcn_exp2f(x); }
__device__ __forceinline__ float fast_log2(float x) { return __builtin_amdgcn_logf(x); }

// exp(z) as a double, via 2^n * exp2(r).  z in ~[-700, +700] is safe.
__device__ __forceinline__ double exp_double(float z) {
    float y = z * LOG2E;
    float n = rintf(y);
    float r = y - n;                 // |r| <= 0.5
    float f = fast_exp2(r);
    long long e = (long long)n + 1023;
    if (e < 1)    e = 1;
    if (e > 2046) e = 2046;
    double scale = __longlong_as_double(e << 52);
    return (double)f * scale;
}

// log2 of a positive normal double, to float precision.
__device__ __forceinline__ float log2_of_double(double v) {
    unsigned long long b = __double_as_longlong(v);
    int ex = (int)((b >> 52) & 0x7FFULL) - 1023;
    double m = __longlong_as_double((b & 0xFFFFFFFFFFFFFULL) | 0x3FF0000000000000ULL);
    return (float)ex + fast_log2((float)m);
}

// ---------------------------------------------------------------------------
// Build transposed fp16-SPLIT weight matrix:  Wt = [Wq | Wk]^T as [n=256][k=256]
// with hi = fp16(w), lo = fp16(w - hi).  Enables compensated-fp16 MFMA GEMM
// that reproduces the fp32 result to ~2^-22 (output is fp16-rounded anyway).
// ---------------------------------------------------------------------------
__global__ __launch_bounds__(256) void convert_w(
    const float* __restrict__ Wq, const float* __restrict__ Wk,
    _Float16* __restrict__ Wt_hi, _Float16* __restrict__ Wt_lo)
{
    int t = blockIdx.x * 256 + threadIdx.x;    // 65536 total
    int n = t >> 8;
    int k = t & 255;
    float x = (n < 128) ? Wq[k * 128 + n] : Wk[k * 128 + (n - 128)];
    _Float16 hi = (_Float16)x;
    _Float16 lo = (_Float16)(x - (float)hi);
    Wt_hi[n * 256 + k] = hi;
    Wt_lo[n * 256 + k] = lo;
}

// ---------------------------------------------------------------------------
// Compensated-fp16 MFMA GEMM.  X = [Xu; Xi] (75000 x 256) fp32, split on the
// fly to hi/lo fp16 in LDS.  D = Xhi*Whi + Xlo*Whi + Xhi*Wlo (f32 accum) ==
// fp32 GEMM to ~2^-22.  Block: 64 rows x 256 cols, K-step 64, 4 waves (each
// a 64-col slice).  mfma_f32_16x16x32_f16 fragments:
//   A: lane l holds A[l&15][(l>>4)*8 + j]   (16B contiguous k -> ds_read_b128)
//   B: lane l holds B[(l>>4)*8 + j][l&15]   (16B contiguous k of Wt row n)
//   D: lane l reg q -> row (l>>4)*4+q, col l&15   [m89-verified layout]
// Epilogue: + bias, fp16, interleaved rows QK[r*256 + 0..127]=Q, [128..255]=K.
// ---------------------------------------------------------------------------
__global__ __launch_bounds__(256) void gemm_qk_mfma(
    const float* __restrict__ Xu, const float* __restrict__ Xi,
    const _Float16* __restrict__ Wt_hi, const _Float16* __restrict__ Wt_lo,
    const float* __restrict__ bq, const float* __restrict__ bk,
    __half* __restrict__ QK, int U, int I)
{
    __shared__ _Float16 Ah[64][72];   // +8 pad: conflict-free ds_read_b128
    __shared__ _Float16 Al[64][72];

    const int tid  = threadIdx.x;
    const int row0 = blockIdx.x * 64;
    const int wv   = tid >> 6;        // wave 0..3
    const int l    = tid & 63;
    const int lr   = l & 15;
    const int kc   = l >> 4;          // k-chunk 0..3
    const int n0   = wv * 64;
    const int NT   = U + I;

    f32x4 acc[4][4];
#pragma unroll
    for (int i = 0; i < 4; ++i)
#pragma unroll
        for (int j = 0; j < 4; ++j)
            acc[i][j] = (f32x4){0.f, 0.f, 0.f, 0.f};

    // staging role: thread -> (row, 16-half k chunk)
    const int sr = tid >> 2;
    const int sk = (tid & 3) * 16;
    const float* Xrow = nullptr;
    {
        int gr = row0 + sr;
        if (gr < U)       Xrow = &Xu[(size_t)gr * 256];
        else if (gr < NT) Xrow = &Xi[(size_t)(gr - U) * 256];
    }

    for (int k0 = 0; k0 < 256; k0 += 64) {
        // ---- stage A tile (64 x 64) as hi/lo fp16 ----
        {
            float x[16];
            if (Xrow) {
                float4 v0 = *(const float4*)&Xrow[k0 + sk + 0];
                float4 v1 = *(const float4*)&Xrow[k0 + sk + 4];
                float4 v2 = *(const float4*)&Xrow[k0 + sk + 8];
                float4 v3 = *(const float4*)&Xrow[k0 + sk + 12];
                x[0]=v0.x; x[1]=v0.y; x[2]=v0.z; x[3]=v0.w;
                x[4]=v1.x; x[5]=v1.y; x[6]=v1.z; x[7]=v1.w;
                x[8]=v2.x; x[9]=v2.y; x[10]=v2.z; x[11]=v2.w;
                x[12]=v3.x; x[13]=v3.y; x[14]=v3.z; x[15]=v3.w;
            } else {
#pragma unroll
                for (int q = 0; q < 16; ++q) x[q] = 0.f;
            }
            _Float16 hi[16], lo[16];
#pragma unroll
            for (int q = 0; q < 16; ++q) {
                hi[q] = (_Float16)x[q];
                lo[q] = (_Float16)(x[q] - (float)hi[q]);
            }
            *(f16x8*)&Ah[sr][sk]     = *(const f16x8*)&hi[0];
            *(f16x8*)&Ah[sr][sk + 8] = *(const f16x8*)&hi[8];
            *(f16x8*)&Al[sr][sk]     = *(const f16x8*)&lo[0];
            *(f16x8*)&Al[sr][sk + 8] = *(const f16x8*)&lo[8];
        }
        __syncthreads();

#pragma unroll
        for (int kk = 0; kk < 2; ++kk) {
            const int kof = kk * 32 + kc * 8;
            f16x8 ah[4], al[4];
#pragma unroll
            for (int i = 0; i < 4; ++i) {
                ah[i] = *(const f16x8*)&Ah[i * 16 + lr][kof];
                al[i] = *(const f16x8*)&Al[i * 16 + lr][kof];
            }
#pragma unroll
            for (int j = 0; j < 4; ++j) {
                const size_t wo = (size_t)(n0 + j * 16 + lr) * 256 + k0 + kof;
                f16x8 bh = *(const f16x8*)&Wt_hi[wo];
                f16x8 bl = *(const f16x8*)&Wt_lo[wo];
#pragma unroll
                for (int i = 0; i < 4; ++i) {
                    acc[i][j] = __builtin_amdgcn_mfma_f32_16x16x32_f16(ah[i], bh, acc[i][j], 0, 0, 0);
                    acc[i][j] = __builtin_amdgcn_mfma_f32_16x16x32_f16(al[i], bh, acc[i][j], 0, 0, 0);
                    acc[i][j] = __builtin_amdgcn_mfma_f32_16x16x32_f16(ah[i], bl, acc[i][j], 0, 0, 0);
                }
            }
        }
        __syncthreads();
    }

    // ---- epilogue: bias + fp16 store ----
    float bias[4];
#pragma unroll
    for (int j = 0; j < 4; ++j) {
        int col = n0 + j * 16 + lr;
        bias[j] = (col < 128) ? bq[col] : bk[col - 128];
    }
#pragma unroll
    for (int i = 0; i < 4; ++i) {
#pragma unroll
        for (int q = 0; q < 4; ++q) {
            int gr = row0 + i * 16 + kc * 4 + q;
            if (gr < NT) {
#pragma unroll
                for (int j = 0; j < 4; ++j) {
                    int col = n0 + j * 16 + lr;
                    QK[(size_t)gr * 256 + col] = __float2half_rn(acc[i][j][q] + bias[j]);
                }
            }
        }
    }
}

// ---------------------------------------------------------------------------
// Fused BOTH-direction edge kernel, 8 lanes per edge (R4 version — measured
// at the gather-path ceiling ~3.9 TB/s; do not re-tune lanes/MLP).
// ---------------------------------------------------------------------------
__global__ __launch_bounds__(256) void edge_w_both(
    const __half* __restrict__ QK,
    const int* __restrict__ rows, const int* __restrict__ cols,
    const float* __restrict__ noise_ui, const float* __restrict__ noise_iu,
    float* __restrict__ out, double* __restrict__ seg_sumd, int U, int E)
{
    const int gtid = blockIdx.x * 256 + threadIdx.x;
    const int eid  = gtid >> 3;
    if (eid >= E) return;
    const int hl = threadIdx.x & 7;

    const int r = __builtin_nontemporal_load(&rows[eid]);
    const int c = __builtin_nontemporal_load(&cols[eid]);
    const __half* urow = QK + (size_t)r * 256;
    const __half* irow = QK + (size_t)(U + c) * 256;

    const uint4 qu0 = *(const uint4*)(urow + hl * 16);
    const uint4 qu1 = *(const uint4*)(urow + hl * 16 + 8);
    const uint4 ku0 = *(const uint4*)(urow + 128 + hl * 16);
    const uint4 ku1 = *(const uint4*)(urow + 128 + hl * 16 + 8);
    const uint4 qi0 = *(const uint4*)(irow + hl * 16);
    const uint4 qi1 = *(const uint4*)(irow + hl * 16 + 8);
    const uint4 ki0 = *(const uint4*)(irow + 128 + hl * 16);
    const uint4 ki1 = *(const uint4*)(irow + 128 + hl * 16 + 8);

    float d0 = 0.0f, d1 = 0.0f;
    {
        const half2v* a0 = (const half2v*)&qu0;
        const half2v* b0 = (const half2v*)&ki0;
        const half2v* a1 = (const half2v*)&qi0;
        const half2v* b1 = (const half2v*)&ku0;
#pragma unroll
        for (int t = 0; t < 4; ++t) {
            d0 = __builtin_amdgcn_fdot2(a0[t], b0[t], d0, false);
            d1 = __builtin_amdgcn_fdot2(a1[t], b1[t], d1, false);
        }
        const half2v* a0b = (const half2v*)&qu1;
        const half2v* b0b = (const half2v*)&ki1;
        const half2v* a1b = (const half2v*)&qi1;
        const half2v* b1b = (const half2v*)&ku1;
#pragma unroll
        for (int t = 0; t < 4; ++t) {
            d0 = __builtin_amdgcn_fdot2(a0b[t], b0b[t], d0, false);
            d1 = __builtin_amdgcn_fdot2(a1b[t], b1b[t], d1, false);
        }
    }
    d0 += __shfl_xor(d0, 4);  d1 += __shfl_xor(d1, 4);
    d0 += __shfl_xor(d0, 2);  d1 += __shfl_xor(d1, 2);
    d0 += __shfl_xor(d0, 1);  d1 += __shfl_xor(d1, 1);

    if (hl < 2) {
        const int g  = hl;                      // 0 = ui, 1 = iu
        const float d  = g ? d1 : d0;
        const float nz = g ? __builtin_nontemporal_load(&noise_iu[eid])
                           : __builtin_nontemporal_load(&noise_ui[eid]);
        const float zz = (d - __logf(-__logf(nz))) * TAU_INV;
        const int s  = g ? (U + c) : r;
        __builtin_nontemporal_store(zz, &out[(size_t)g * E + eid]);
        atomicAdd(&seg_sumd[s], exp_double(zz));
    }
}

// ---------------------------------------------------------------------------
// out = exp(z) / S[seg]  computed as  exp2(z*log2e - log2(S)).  Vectorized
// 2 elems/thread with proper dwordx2 loads (R3 form — R4's scalar
// nontemporal rewrite was the suspected +10us regression).
// ---------------------------------------------------------------------------
__global__ void edge_norm2v(float* __restrict__ z,
                            const int* __restrict__ rows, const int* __restrict__ cols,
                            const double* __restrict__ seg_sumd, int U, int E)
{
    int p = blockIdx.x * blockDim.x + threadIdx.x;
    int i = p * 2;
    if (i >= 2 * E) return;
    const bool iu  = (i >= E);
    const int base = iu ? (i - E) : i;
    const int off  = iu ? U : 0;
    const int* idx = iu ? cols : rows;
    int2 rc   = *(const int2*)&idx[base];
    float2 zz = *(const float2*)&z[i];
    float l0 = log2_of_double(seg_sumd[off + rc.x]);
    float l1 = log2_of_double(seg_sumd[off + rc.y]);
    float o0 = fast_exp2(zz.x * LOG2E - l0);
    float o1 = fast_exp2(zz.y * LOG2E - l1);
    *(float2*)&z[i] = make_float2(o0, o1);
}

__global__ void edge_norm2(float* __restrict__ z,
                           const int* __restrict__ rows, const int* __restrict__ cols,
                           const double* __restrict__ seg_sumd, int U, int E)
{
    int i = blockIdx.x * blockDim.x + threadIdx.x;
    if (i >= 2 * E) return;
    int s = (i < E) ? rows[i] : (U + cols[i - E]);
    float l = log2_of_double(seg_sumd[s]);
    z[i] = fast_exp2(z[i] * LOG2E - l);
}

// ---------------------------------------------------------------------------
extern "C" void kernel_launch(void* const* d_in, const int* in_sizes, int n_in,
                              void* d_out, int out_size, void* d_ws, size_t ws_size,
                              hipStream_t stream)
{
    const float* user_embed = (const float*)d_in[0];
    const float* item_embed = (const float*)d_in[1];
    const float* Wq = (const float*)d_in[2];
    const float* bq = (const float*)d_in[3];
    const float* Wk = (const float*)d_in[4];
    const float* bk = (const float*)d_in[5];
    const int* ui_rows    = (const int*)d_in[6];
    const int* ui_cols    = (const int*)d_in[7];
    const float* noise_ui = (const float*)d_in[8];
    const float* noise_iu = (const float*)d_in[9];

    const int H = in_sizes[3];           // 128
    const int D = in_sizes[2] / H;       // 256
    const int U = in_sizes[0] / D;       // 50000
    const int I = in_sizes[1] / D;       // 25000
    const int E = in_sizes[6];           // 1600000

    const int nseg = U + I;

    // workspace: QK fp16 (U+I)x256 | seg_sumd double | Wt_hi | Wt_lo
    char* wsc = (char*)d_ws;
    __half* QK = (__half*)wsc;          wsc += (size_t)nseg * 256 * sizeof(__half);
    double* seg_sumd = (double*)wsc;    wsc += (size_t)nseg * sizeof(double);
    _Float16* Wt_hi = (_Float16*)wsc;   wsc += (size_t)256 * 256 * sizeof(_Float16);
    _Float16* Wt_lo = (_Float16*)wsc;   wsc += (size_t)256 * 256 * sizeof(_Float16);

    float* out = (float*)d_out;         // [z_ui | z_iu] -> normalized in place

    hipMemsetAsync(seg_sumd, 0, (size_t)nseg * sizeof(double), stream);

    convert_w<<<256, 256, 0, stream>>>(Wq, Wk, Wt_hi, Wt_lo);

    const int gblocks = (nseg + 63) / 64;
    gemm_qk_mfma<<<gblocks, 256, 0, stream>>>(user_embed, item_embed,
                                              Wt_hi, Wt_lo, bq, bk, QK, U, I);

    const int eblocks = (int)(((long long)E * 8 + 255) / 256);
    edge_w_both<<<eblocks, 256, 0, stream>>>(QK, ui_rows, ui_cols,
                                             noise_ui, noise_iu,
                                             out, seg_sumd, U, E);

    if ((E & 1) == 0) {
        const int vblocks = (E + 255) / 256;   // E pairs cover 2E elements
        edge_norm2v<<<vblocks, 256, 0, stream>>>(out, ui_rows, ui_cols,
                                                 seg_sumd, U, E);
    } else {
        const int sblocks = (2 * E + 255) / 256;
        edge_norm2<<<sblocks, 256, 0, stream>>>(out, ui_rows, ui_cols,
                                                seg_sumd, U, E);
    }
}